// Round 15
// baseline (1186.594 us; speedup 1.0000x reference)
//
#include <hip/hip_runtime.h>
#include <stdint.h>
#include <stddef.h>

#define BB     16384
#define TD     768
#define ID_    1024
#define HID    1024
#define OD     1024
#define NE     8
#define CB     2048
#define CAPT   33792   // 32768 assignments + up to 8*127 pad (x128 padding)
#define GIN    1792    // TD + ID_

typedef __bf16 bf16;
typedef __bf16 bf16x4 __attribute__((ext_vector_type(4)));
typedef __bf16 bf16x8 __attribute__((ext_vector_type(8)));
typedef float  f32x4  __attribute__((ext_vector_type(4)));

struct Top2 { int e0, e1; float w0, w1; };
struct Slot2 { int p0, p1; };

__device__ __forceinline__ void gload16(void* lds, const void* g) {
#if __has_builtin(__builtin_amdgcn_global_load_lds)
  __builtin_amdgcn_global_load_lds(
      (const __attribute__((address_space(1))) void*)g,
      (__attribute__((address_space(3))) void*)lds, 16, 0, 0);
#else
  *(int4*)lds = *(const int4*)g;   // reg-staged fallback
#endif
}

// ---------------- transpose + f32->bf16 convert: src[R][C] f32 -> dst[C][R] bf16
__global__ void transpose_cvt(const float* __restrict__ src, bf16* __restrict__ dst,
                              int R, int C) {
  src += (size_t)blockIdx.z * R * C;
  dst += (size_t)blockIdx.z * R * C;
  __shared__ float tile[64][65];
  const int r0 = blockIdx.y * 64, c0 = blockIdx.x * 64;
  const int t = threadIdx.x;
#pragma unroll
  for (int i = 0; i < 16; ++i) {
    int e = i * 256 + t;
    int ii = e >> 6, jj = e & 63;
    tile[ii][jj] = src[(size_t)(r0 + ii) * C + (c0 + jj)];
  }
  __syncthreads();
#pragma unroll
  for (int i = 0; i < 16; ++i) {
    int e = i * 256 + t;
    int ii = e >> 6, jj = e & 63;
    dst[(size_t)(c0 + ii) * R + (r0 + jj)] = (bf16)tile[jj][ii];
  }
}

// ---------------- bf16 row-major copy of [Wt; Wi] -> Xb[1792][1024]
__global__ __launch_bounds__(256)
void cast_x(const float* __restrict__ Wt, const float* __restrict__ Wi,
            bf16* __restrict__ Xb) {
  const size_t i = ((size_t)blockIdx.x * 256 + threadIdx.x) * 8;
  const float* s = (i < (size_t)TD * HID) ? (Wt + i) : (Wi + (i - (size_t)TD * HID));
  f32x4 a = *(const f32x4*)s;
  f32x4 b = *(const f32x4*)(s + 4);
  bf16x8 o;
#pragma unroll
  for (int j = 0; j < 4; ++j) { o[j] = (bf16)a[j]; o[4 + j] = (bf16)b[j]; }
  *(bf16x8*)(Xb + i) = o;
}

// ---------------- folded FFN1 bias: b1eff[e][n] = b1[e][n] + bt.W1[e][:1024,n] + bi.W1[e][1024:,n]
__global__ __launch_bounds__(256)
void b1eff_k(const bf16* __restrict__ W1T, const float* __restrict__ bt,
             const float* __restrict__ bi, const float* __restrict__ b1,
             float* __restrict__ out) {
  const int o = blockIdx.x * 256 + threadIdx.x;   // < NE*HID
  const int e = o >> 10, n = o & 1023;
  const bf16* wr = W1T + ((size_t)e * HID + n) * CB;
  float s = b1[o];
  for (int h8 = 0; h8 < HID / 8; ++h8) {
    bf16x8 wa = *(const bf16x8*)(wr + h8 * 8);
    bf16x8 wb = *(const bf16x8*)(wr + HID + h8 * 8);
#pragma unroll
    for (int j = 0; j < 8; ++j)
      s += bt[h8 * 8 + j] * (float)wa[j] + bi[h8 * 8 + j] * (float)wb[j];
  }
  out[o] = s;
}

// ---------------- fused gating matrices in fp64, wave-parallel (one wave/output)
__global__ __launch_bounds__(256)
void fuse_w(const float* __restrict__ Wt, const float* __restrict__ Wi,
            const float* __restrict__ Wg, const float* __restrict__ bt,
            const float* __restrict__ bi, const float* __restrict__ bg,
            double* __restrict__ WgF, double* __restrict__ bgd) {
  const int o = blockIdx.x * 4 + (threadIdx.x >> 6);   // wave-global output id
  const int lane = threadIdx.x & 63;
  if (o >= (GIN + 1) * NE) return;
  const int idx = o >> 3, e = o & 7;
  double s = 0.0;
  if (idx < TD) {
    const float* wrow = Wt + (size_t)idx * HID;
    for (int h = lane; h < HID; h += 64)
      s += (double)wrow[h] * (double)Wg[(size_t)h * NE + e];
  } else if (idx < GIN) {
    const float* wrow = Wi + (size_t)(idx - TD) * HID;
    for (int h = lane; h < HID; h += 64)
      s += (double)wrow[h] * (double)Wg[(size_t)(HID + h) * NE + e];
  } else {
    for (int h = lane; h < HID; h += 64) {
      s += (double)bt[h] * (double)Wg[(size_t)h * NE + e];
      s += (double)bi[h] * (double)Wg[(size_t)(HID + h) * NE + e];
    }
  }
#pragma unroll
  for (int off = 32; off > 0; off >>= 1) s += __shfl_down(s, off);
  if (lane == 0) {
    if (idx < GIN) WgF[(size_t)e * GIN + idx] = s;
    else           bgd[e] = s + (double)bg[e];
  }
}

// ---------------- routing pass 1: LDS-staged fp64 weights, 64 rows per block.
__global__ __launch_bounds__(1024)
void route1(const float* __restrict__ text, const float* __restrict__ image,
            const float* __restrict__ noise,
            const double* __restrict__ WgF, const double* __restrict__ bgd,
            bf16* __restrict__ text_b, bf16* __restrict__ image_b,
            Top2* __restrict__ top2, int* __restrict__ counts) {
  __shared__ double wg[NE * GIN];        // 112 KiB
  __shared__ int lcnt[NE];
  const int t = threadIdx.x;
  if (t < NE) lcnt[t] = 0;
  {
    const ulonglong2* src = (const ulonglong2*)WgF;
    ulonglong2* dst = (ulonglong2*)wg;
#pragma unroll
    for (int i = 0; i < (NE * GIN) / 2 / 1024; ++i)
      dst[i * 1024 + t] = src[i * 1024 + t];
  }
  __syncthreads();

  const int wave = t >> 6, lane = t & 63;
  const int row0 = blockIdx.x * 64;
#pragma unroll
  for (int rr = 0; rr < 4; ++rr) {
    const int row = row0 + wave + rr * 16;
    const float* tr = text + (size_t)row * TD;
    const float* ir = image + (size_t)row * ID_;
    float xv[28];
#pragma unroll
    for (int c = 0; c < 12; ++c) xv[c] = tr[lane + 64 * c];
#pragma unroll
    for (int c = 0; c < 16; ++c) xv[12 + c] = ir[lane + 64 * c];
    bf16* tb = text_b + (size_t)row * TD;
    bf16* ib = image_b + (size_t)row * ID_;
#pragma unroll
    for (int c = 0; c < 12; ++c) tb[lane + 64 * c] = (bf16)xv[c];
#pragma unroll
    for (int c = 0; c < 16; ++c) ib[lane + 64 * c] = (bf16)xv[12 + c];

    double acc[NE];
#pragma unroll
    for (int e = 0; e < NE; ++e) acc[e] = 0.0;
#pragma unroll
    for (int c = 0; c < 28; ++c) {
      const double vd = (double)xv[c];
      const int idx = lane + 64 * c;
#pragma unroll
      for (int e = 0; e < NE; ++e) acc[e] = fma(vd, wg[e * GIN + idx], acc[e]);
    }
#pragma unroll
    for (int off = 32; off > 0; off >>= 1) {
#pragma unroll
      for (int e = 0; e < NE; ++e) acc[e] += __shfl_down(acc[e], off);
    }
    if (lane == 0) {
      float nz[NE];
#pragma unroll
      for (int e = 0; e < NE; ++e)
        nz[e] = (float)(acc[e] + bgd[e]) + noise[(size_t)row * NE + e];
      int i0 = 0;
#pragma unroll
      for (int e = 1; e < NE; ++e) if (nz[e] > nz[i0]) i0 = e;
      int i1 = (i0 == 0) ? 1 : 0;
#pragma unroll
      for (int e = 0; e < NE; ++e) if (e != i0 && nz[e] > nz[i1]) i1 = e;
      float tt = expf(nz[i1] - nz[i0]);
      float w0 = 1.0f / (1.0f + tt);
      float w1 = tt / (1.0f + tt);
      Top2 rec; rec.e0 = i0; rec.e1 = i1; rec.w0 = w0; rec.w1 = w1;
      top2[row] = rec;
      atomicAdd(&lcnt[i0], 1);
      atomicAdd(&lcnt[i1], 1);
    }
  }
  __syncthreads();
  if (t < NE) atomicAdd(&counts[t], lcnt[t]);
}

// ---------------- scan: offsets (padded to x128), init pos
__global__ void scan_pad(const int* __restrict__ counts, int* __restrict__ offsets,
                         int* __restrict__ padded, int* __restrict__ pos,
                         int* __restrict__ rows_list, float* __restrict__ wgt_list) {
  __shared__ int s_off[NE], s_cnt[NE], s_pad[NE];
  if (threadIdx.x == 0) {
    int off = 0;
    for (int e = 0; e < NE; ++e) {
      int c = counts[e];
      int pd = (c + 127) & ~127;
      s_cnt[e] = c; s_pad[e] = pd; s_off[e] = off;
      offsets[e] = off; padded[e] = pd; pos[e] = off;
      off += pd;
    }
    offsets[NE] = off;
  }
  __syncthreads();
  for (int e = 0; e < NE; ++e) {
    for (int i = s_cnt[e] + threadIdx.x; i < s_pad[e]; i += blockDim.x) {
      rows_list[s_off[e] + i] = 0;
      wgt_list[s_off[e] + i] = 0.0f;
    }
  }
}

// ---------------- routing pass 2: block-aggregated scatter + slot map
__global__ void route2(const Top2* __restrict__ top2, int* __restrict__ pos,
                       int* __restrict__ rows_list, float* __restrict__ wgt_list,
                       Slot2* __restrict__ slots) {
  __shared__ int lcnt[NE], lbase[NE];
  if (threadIdx.x < NE) lcnt[threadIdx.x] = 0;
  __syncthreads();
  const int r = blockIdx.x * 256 + threadIdx.x;
  Top2 tt = top2[r];
  int s0 = atomicAdd(&lcnt[tt.e0], 1);
  int s1 = atomicAdd(&lcnt[tt.e1], 1);
  __syncthreads();
  if (threadIdx.x < NE)
    lbase[threadIdx.x] = atomicAdd(&pos[threadIdx.x], lcnt[threadIdx.x]);
  __syncthreads();
  int p0 = lbase[tt.e0] + s0;
  rows_list[p0] = r; wgt_list[p0] = tt.w0;
  int p1 = lbase[tt.e1] + s1;
  rows_list[p1] = r; wgt_list[p1] = tt.w1;
  Slot2 sl; sl.p0 = p0; sl.p1 = p1;
  slots[r] = sl;
}

// ---------------- final combine: out[row] = pair[p0] + pair[p1]
__global__ __launch_bounds__(256)
void combine(const bf16* __restrict__ pairb, const Slot2* __restrict__ slots,
             float* __restrict__ out) {
  const int row = blockIdx.x;
  const Slot2 s = slots[row];
  const int t = threadIdx.x;
  const bf16x4 a = *(const bf16x4*)(pairb + (size_t)s.p0 * OD + t * 4);
  const bf16x4 b = *(const bf16x4*)(pairb + (size_t)s.p1 * OD + t * 4);
  f32x4 r;
#pragma unroll
  for (int j = 0; j < 4; ++j) r[j] = (float)a[j] + (float)b[j];
  *(f32x4*)(out + (size_t)row * OD + t * 4) = r;
}

// ========= 128x128 BK=64 SINGLE-buffered bf16 MFMA GEMM (m97 structure) =========
// r11/r13/r14-proven best (FFN1 963 TF).  4 waves (2Mx2N), 64x64/wave, 32 KiB
// LDS single buffer; vmcnt(0) + 2 barriers per 64-K step.  NEW r15:
// __launch_bounds__(256,5) -> 5 blocks/CU (LDS 5x32 KiB = 160 KiB exactly;
// VGPR 64 far under cap) -- occupancy is the proven dominant term (r8-r12).
// Swizzle: source/read octet ^= (row&7) -> conflict-free.  1D grid XCD decode
// (A-tile's 8 N-blocks on one XCD) for MODE 1/2; 2D grid for MODE 3.
// MODE 1: expert FFN1, A gathered from TWO sources (text rows kt<12, image
//         rows kt>=12) -> h (bf16, +b1eff, relu)
// MODE 2: expert FFN2 -> pairbuf (bf16, w*(acc+b2))
// MODE 3: weight preprocess, MERGED halves (x<6: text half, else image half):
//         W1effT[e][n][coloff+k] = sum_h Xb_half[k][h] * W1T[e][n][half*HID+h]

#define BARe  do { __builtin_amdgcn_s_barrier(); __builtin_amdgcn_sched_barrier(0); } while (0)
#define VMC0  asm volatile("s_waitcnt vmcnt(0)" ::: "memory")
#define PRIO1 __builtin_amdgcn_s_setprio(1)
#define PRIO0 __builtin_amdgcn_s_setprio(0)

template<int MODE>
__global__ __launch_bounds__(256, 5)
void gemm128(const bf16* __restrict__ A, const bf16* __restrict__ A2,
             const bf16* __restrict__ BT, const float* __restrict__ bias,
             bf16* __restrict__ outb,
             const int* __restrict__ rows_list, const float* __restrict__ wgt_list,
             const int* __restrict__ offsets, const int* __restrict__ padded,
             int K, int lda, int ldb, int ldout, int coloff) {
  __shared__ bf16 As[128 * 64];   // 16 KiB
  __shared__ bf16 Bs[128 * 64];   // 16 KiB
  const int t = threadIdx.x;
  const int lane = t & 63, w = t >> 6;
  const int wm = w >> 1, wn = w & 1;

  int mblk, nblk;
  if constexpr (MODE == 3) {
    const int e = blockIdx.z;
    const int half = (blockIdx.x >= TD / 128) ? 1 : 0;
    nblk = blockIdx.x - half * (TD / 128);
    mblk = blockIdx.y;
    A += (size_t)e * HID * CB + (size_t)half * HID;   // k-offset into W1T rows
    BT += (size_t)half * TD * HID;                    // Xb image section
    outb += (size_t)e * HID * GIN;
    coloff = half * TD;
  } else {
    const int bid = blockIdx.x;
    const int xcd = bid & 7, sdec = bid >> 3;
    nblk = sdec & 7; mblk = (sdec >> 3) * 8 + xcd;
  }

  long base = 0;
  if constexpr (MODE == 1 || MODE == 2) {
    const int e = blockIdx.z;
    if (mblk * 128 >= padded[e]) return;
    base = offsets[e];
    if constexpr (MODE == 1) { BT += (size_t)e * HID * GIN; bias += e * HID; }
    else                     { BT += (size_t)e * OD * HID;  bias += e * OD; }
  }

  // staging: thread t, sub-load j (0..3): row = j*32 + (t>>3), octet c = t&7.
  // Source octet pre-swizzled: c ^ (row&7); row&7 == (t>>3)&7 for all j.
  const int scol = ((t & 7) ^ ((t >> 3) & 7)) * 8;
  const bf16* aptr[4]; const bf16* aptr2[4]; const bf16* bptr[4]; int ldso[4];
#pragma unroll
  for (int j = 0; j < 4; ++j) {
    const int row = j * 32 + (t >> 3);
    if constexpr (MODE == 1) {
      const long ga = rows_list[base + (long)mblk * 128 + row];
      aptr[j]  = A  + ga * TD  + scol;
      aptr2[j] = A2 + ga * ID_ + scol;
    } else if constexpr (MODE == 2) {
      const long ga = base + (long)mblk * 128 + row;
      aptr[j] = A + ga * lda + scol;
    } else {
      aptr[j] = A + (size_t)(mblk * 128 + row) * lda + scol;
    }
    bptr[j] = BT + (size_t)(nblk * 128 + row) * ldb + scol;
    ldso[j] = (j * 256 + t) * 8;
  }

  // fragment reads (kk=0): logical octet o = lane>>4; physical = o ^ (fr&7);
  // kk=1 flips octet bit2 -> element offset ^ 32.
  const int fr = lane & 15, hi = lane >> 4;
  const int rsw = hi ^ (fr & 7);
  int a_off[4], b_off[4];
#pragma unroll
  for (int f = 0; f < 4; ++f) {
    a_off[f] = ((wm * 64 + f * 16 + fr) * 8 + rsw) * 8;
    b_off[f] = ((wn * 64 + f * 16 + fr) * 8 + rsw) * 8;
  }

  f32x4 acc[4][4];
#pragma unroll
  for (int i = 0; i < 4; ++i)
#pragma unroll
    for (int j = 0; j < 4; ++j)
#pragma unroll
      for (int r = 0; r < 4; ++r) acc[i][j][r] = 0.0f;

  const int NKT = K >> 6;

  auto stage = [&](int kt) {
    if constexpr (MODE == 1) {
      if (kt < TD / 64) {
#pragma unroll
        for (int j = 0; j < 4; ++j) gload16(&As[ldso[j]], aptr[j] + (size_t)kt * 64);
      } else {
#pragma unroll
        for (int j = 0; j < 4; ++j)
          gload16(&As[ldso[j]], aptr2[j] + (size_t)(kt - TD / 64) * 64);
      }
    } else {
#pragma unroll
      for (int j = 0; j < 4; ++j) gload16(&As[ldso[j]], aptr[j] + (size_t)kt * 64);
    }
#pragma unroll
    for (int j = 0; j < 4; ++j) gload16(&Bs[ldso[j]], bptr[j] + (size_t)kt * 64);
  };

  stage(0);
  for (int kt = 0; kt < NKT; ++kt) {
    VMC0;                              // tile kt's 8 loads landed
    BARe;                              // visible to all waves
#pragma unroll
    for (int kk = 0; kk < 2; ++kk) {
      bf16x8 af[4], bfr[4];
#pragma unroll
      for (int f = 0; f < 4; ++f) af[f]  = *(const bf16x8*)(&As[a_off[f] ^ (kk * 32)]);
#pragma unroll
      for (int f = 0; f < 4; ++f) bfr[f] = *(const bf16x8*)(&Bs[b_off[f] ^ (kk * 32)]);
      PRIO1;
#pragma unroll
      for (int mf = 0; mf < 4; ++mf)
#pragma unroll
        for (int nf = 0; nf < 4; ++nf)
          acc[mf][nf] = __builtin_amdgcn_mfma_f32_16x16x32_bf16(af[mf], bfr[nf],
                                                                acc[mf][nf], 0, 0, 0);
      PRIO0;
    }
    BARe;                              // all waves done reading this buffer
    if (kt + 1 < NKT) stage(kt + 1);   // overwrite with next tile
  }

  // epilogue: D row = (lane>>4)*4 + r, col = lane&15
  const int row_h = hi * 4;
#pragma unroll
  for (int nf = 0; nf < 4; ++nf) {
    const int gcol = nblk * 128 + wn * 64 + nf * 16 + fr;
    float bv = 0.0f;
    if constexpr (MODE != 3) bv = bias[gcol];
#pragma unroll
    for (int mf = 0; mf < 4; ++mf) {
      const int rbase = wm * 64 + mf * 16 + row_h;
#pragma unroll
      for (int r = 0; r < 4; ++r) {
        const int rit = rbase + r;
        float v = acc[mf][nf][r] + bv;
        if constexpr (MODE == 1) {
          outb[(size_t)(base + (long)mblk * 128 + rit) * ldout + gcol] =
              (bf16)fmaxf(v, 0.0f);
        } else if constexpr (MODE == 2) {
          const long li = base + (long)mblk * 128 + rit;
          const float wgt = wgt_list[li];
          outb[(size_t)li * ldout + gcol] = (bf16)(wgt * v);
        } else {
          outb[((size_t)mblk * 128 + rit) * ldout + coloff + gcol] = (bf16)v;
        }
      }
    }
  }
}

extern "C" void kernel_launch(void* const* d_in, const int* in_sizes, int n_in,
                              void* d_out, int out_size, void* d_ws, size_t ws_size,
                              hipStream_t stream) {
  const float* text  = (const float*)d_in[0];
  const float* image = (const float*)d_in[1];
  const float* noise = (const float*)d_in[2];
  const float* Wt    = (const float*)d_in[3];
  const float* bt    = (const float*)d_in[4];
  const float* Wi    = (const float*)d_in[5];
  const float* bi    = (const float*)d_in[6];
  const float* Wg    = (const float*)d_in[7];
  const float* bg    = (const float*)d_in[8];
  const float* W1    = (const float*)d_in[9];
  const float* b1    = (const float*)d_in[10];
  const float* W2    = (const float*)d_in[11];
  const float* b2    = (const float*)d_in[12];
  float* out = (float*)d_out;

  char* p = (char*)d_ws;
  auto alloc = [&](size_t bytes) {
    char* r = p; p += (bytes + 255) & ~(size_t)255; return r;
  };

  bf16* text_b  = (bf16*)alloc((size_t)BB * TD * 2);
  bf16* image_b = (bf16*)alloc((size_t)BB * ID_ * 2);

  // union region u1: {W1T, W1effT, Xb} (preprocess + FFN1 era) / pairb (FFN2 era).
  // W1T 33.55MB + W1effT 29.36MB + Xb 3.67MB = 66.6MB <= pairb 69.2MB.
  // pairb is first written in FFN2, which launches after the last reader of
  // W1T/Xb (preprocess) and W1effT (FFN1) -- stream-ordered, no overlap.
  const size_t sz_w1t  = (size_t)NE * HID * CB * 2;
  const size_t sz_w1e  = (size_t)NE * HID * GIN * 2;
  const size_t sz_pair = (size_t)CAPT * OD * 2;
  char* u1 = alloc(sz_pair);
  bf16* W1T    = (bf16*)u1;
  bf16* W1effT = (bf16*)(u1 + sz_w1t);
  bf16* Xb     = (bf16*)(u1 + sz_w1t + sz_w1e);
  bf16* pairb  = (bf16*)u1;

  bf16*   W2T      = (bf16*)alloc((size_t)NE * OD * HID * 2);
  bf16*   hbuf     = (bf16*)alloc((size_t)CAPT * HID * 2);
  double* WgF      = (double*)alloc((size_t)NE * GIN * 8);
  double* bgd      = (double*)alloc((size_t)NE * 8);
  float*  b1e      = (float*)alloc((size_t)NE * HID * 4);
  Top2*   top2     = (Top2*)alloc((size_t)BB * sizeof(Top2));
  Slot2*  slots    = (Slot2*)alloc((size_t)BB * sizeof(Slot2));
  int*    counts   = (int*)alloc(NE * 4);
  int*    offsets  = (int*)alloc((NE + 1) * 4);
  int*    padded   = (int*)alloc(NE * 4);
  int*    pos      = (int*)alloc(NE * 4);
  int*    rows_list= (int*)alloc((size_t)CAPT * 4);
  float*  wgt_list = (float*)alloc((size_t)CAPT * 4);

  hipMemsetAsync(counts, 0, NE * 4, stream);

  transpose_cvt<<<dim3(HID / 64, CB / 64, NE), 256, 0, stream>>>(W1, W1T, CB, HID);
  transpose_cvt<<<dim3(OD / 64, HID / 64, NE), 256, 0, stream>>>(W2, W2T, HID, OD);
  cast_x<<<(GIN * HID) / 8 / 256, 256, 0, stream>>>(Wt, Wi, Xb);

  fuse_w<<<((GIN + 1) * NE + 3) / 4, 256, 0, stream>>>(
      Wt, Wi, Wg, bt, bi, bg, WgF, bgd);
  b1eff_k<<<NE * HID / 256, 256, 0, stream>>>(W1T, bt, bi, b1, b1e);
  route1<<<BB / 64, 1024, 0, stream>>>(text, image, noise, WgF, bgd,
                                       text_b, image_b, top2, counts);
  scan_pad<<<1, 256, 0, stream>>>(counts, offsets, padded, pos, rows_list, wgt_list);
  route2<<<BB / 256, 256, 0, stream>>>(top2, pos, rows_list, wgt_list, slots);

  // weight preprocess (merged halves): x<6 -> text half, x>=6 -> image half
  gemm128<3><<<dim3(GIN / 128, HID / 128, NE), 256, 0, stream>>>(
      W1T, nullptr, Xb, nullptr, W1effT, nullptr, nullptr, nullptr, nullptr,
      HID, CB, HID, GIN, 0);
  // expert FFN1 (gathered, two-source A, K=1792) -> h
  gemm128<1><<<dim3(1024, 1, NE), 256, 0, stream>>>(
      text_b, image_b, W1effT, b1e, hbuf, rows_list, nullptr, offsets, padded,
      GIN, 0, GIN, HID, 0);
  // expert FFN2 -> pair buffer (plain bf16 stores)
  gemm128<2><<<dim3(1024, 1, NE), 256, 0, stream>>>(
      hbuf, nullptr, W2T, b2, pairb, rows_list, wgt_list, offsets, padded,
      HID, HID, HID, OD, 0);
  // final: out[row] = pair[p0] + pair[p1]
  combine<<<BB, 256, 0, stream>>>(pairb, slots, out);
}

// Round 16
// 475.262 us; speedup vs baseline: 2.4967x; 2.4967x over previous
//
#include <hip/hip_runtime.h>
#include <stdint.h>
#include <stddef.h>

#define BB     16384
#define TD     768
#define ID_    1024
#define HID    1024
#define OD     1024
#define NE     8
#define CB     2048
#define CAPT   33792   // 32768 assignments + up to 8*127 pad (x128 padding)
#define GIN    1792    // TD + ID_

typedef __bf16 bf16;
typedef __bf16 bf16x4 __attribute__((ext_vector_type(4)));
typedef __bf16 bf16x8 __attribute__((ext_vector_type(8)));
typedef float  f32x4  __attribute__((ext_vector_type(4)));

struct Top2 { int e0, e1; float w0, w1; };
struct Slot2 { int p0, p1; };

__device__ __forceinline__ void gload16(void* lds, const void* g) {
#if __has_builtin(__builtin_amdgcn_global_load_lds)
  __builtin_amdgcn_global_load_lds(
      (const __attribute__((address_space(1))) void*)g,
      (__attribute__((address_space(3))) void*)lds, 16, 0, 0);
#else
  *(int4*)lds = *(const int4*)g;   // reg-staged fallback
#endif
}

// ---------------- transpose + f32->bf16 convert: src[R][C] f32 -> dst[C][R] bf16
__global__ void transpose_cvt(const float* __restrict__ src, bf16* __restrict__ dst,
                              int R, int C) {
  src += (size_t)blockIdx.z * R * C;
  dst += (size_t)blockIdx.z * R * C;
  __shared__ float tile[64][65];
  const int r0 = blockIdx.y * 64, c0 = blockIdx.x * 64;
  const int t = threadIdx.x;
#pragma unroll
  for (int i = 0; i < 16; ++i) {
    int e = i * 256 + t;
    int ii = e >> 6, jj = e & 63;
    tile[ii][jj] = src[(size_t)(r0 + ii) * C + (c0 + jj)];
  }
  __syncthreads();
#pragma unroll
  for (int i = 0; i < 16; ++i) {
    int e = i * 256 + t;
    int ii = e >> 6, jj = e & 63;
    dst[(size_t)(c0 + ii) * R + (r0 + jj)] = (bf16)tile[jj][ii];
  }
}

// ---------------- bf16 row-major copy of [Wt; Wi] -> Xb[1792][1024]
__global__ __launch_bounds__(256)
void cast_x(const float* __restrict__ Wt, const float* __restrict__ Wi,
            bf16* __restrict__ Xb) {
  const size_t i = ((size_t)blockIdx.x * 256 + threadIdx.x) * 8;
  const float* s = (i < (size_t)TD * HID) ? (Wt + i) : (Wi + (i - (size_t)TD * HID));
  f32x4 a = *(const f32x4*)s;
  f32x4 b = *(const f32x4*)(s + 4);
  bf16x8 o;
#pragma unroll
  for (int j = 0; j < 4; ++j) { o[j] = (bf16)a[j]; o[4 + j] = (bf16)b[j]; }
  *(bf16x8*)(Xb + i) = o;
}

// ---------------- folded FFN1 bias: b1eff[e][n] = b1[e][n] + bt.W1[e][:1024,n] + bi.W1[e][1024:,n]
__global__ __launch_bounds__(256)
void b1eff_k(const bf16* __restrict__ W1T, const float* __restrict__ bt,
             const float* __restrict__ bi, const float* __restrict__ b1,
             float* __restrict__ out) {
  const int o = blockIdx.x * 256 + threadIdx.x;   // < NE*HID
  const int e = o >> 10, n = o & 1023;
  const bf16* wr = W1T + ((size_t)e * HID + n) * CB;
  float s = b1[o];
  for (int h8 = 0; h8 < HID / 8; ++h8) {
    bf16x8 wa = *(const bf16x8*)(wr + h8 * 8);
    bf16x8 wb = *(const bf16x8*)(wr + HID + h8 * 8);
#pragma unroll
    for (int j = 0; j < 8; ++j)
      s += bt[h8 * 8 + j] * (float)wa[j] + bi[h8 * 8 + j] * (float)wb[j];
  }
  out[o] = s;
}

// ---------------- fused gating matrices in fp64, wave-parallel (one wave/output)
__global__ __launch_bounds__(256)
void fuse_w(const float* __restrict__ Wt, const float* __restrict__ Wi,
            const float* __restrict__ Wg, const float* __restrict__ bt,
            const float* __restrict__ bi, const float* __restrict__ bg,
            double* __restrict__ WgF, double* __restrict__ bgd) {
  const int o = blockIdx.x * 4 + (threadIdx.x >> 6);   // wave-global output id
  const int lane = threadIdx.x & 63;
  if (o >= (GIN + 1) * NE) return;
  const int idx = o >> 3, e = o & 7;
  double s = 0.0;
  if (idx < TD) {
    const float* wrow = Wt + (size_t)idx * HID;
    for (int h = lane; h < HID; h += 64)
      s += (double)wrow[h] * (double)Wg[(size_t)h * NE + e];
  } else if (idx < GIN) {
    const float* wrow = Wi + (size_t)(idx - TD) * HID;
    for (int h = lane; h < HID; h += 64)
      s += (double)wrow[h] * (double)Wg[(size_t)(HID + h) * NE + e];
  } else {
    for (int h = lane; h < HID; h += 64) {
      s += (double)bt[h] * (double)Wg[(size_t)h * NE + e];
      s += (double)bi[h] * (double)Wg[(size_t)(HID + h) * NE + e];
    }
  }
#pragma unroll
  for (int off = 32; off > 0; off >>= 1) s += __shfl_down(s, off);
  if (lane == 0) {
    if (idx < GIN) WgF[(size_t)e * GIN + idx] = s;
    else           bgd[e] = s + (double)bg[e];
  }
}

// ---------------- routing pass 1: LDS-staged fp64 weights, 64 rows per block.
__global__ __launch_bounds__(1024)
void route1(const float* __restrict__ text, const float* __restrict__ image,
            const float* __restrict__ noise,
            const double* __restrict__ WgF, const double* __restrict__ bgd,
            bf16* __restrict__ text_b, bf16* __restrict__ image_b,
            Top2* __restrict__ top2, int* __restrict__ counts) {
  __shared__ double wg[NE * GIN];        // 112 KiB
  __shared__ int lcnt[NE];
  const int t = threadIdx.x;
  if (t < NE) lcnt[t] = 0;
  {
    const ulonglong2* src = (const ulonglong2*)WgF;
    ulonglong2* dst = (ulonglong2*)wg;
#pragma unroll
    for (int i = 0; i < (NE * GIN) / 2 / 1024; ++i)
      dst[i * 1024 + t] = src[i * 1024 + t];
  }
  __syncthreads();

  const int wave = t >> 6, lane = t & 63;
  const int row0 = blockIdx.x * 64;
#pragma unroll
  for (int rr = 0; rr < 4; ++rr) {
    const int row = row0 + wave + rr * 16;
    const float* tr = text + (size_t)row * TD;
    const float* ir = image + (size_t)row * ID_;
    float xv[28];
#pragma unroll
    for (int c = 0; c < 12; ++c) xv[c] = tr[lane + 64 * c];
#pragma unroll
    for (int c = 0; c < 16; ++c) xv[12 + c] = ir[lane + 64 * c];
    bf16* tb = text_b + (size_t)row * TD;
    bf16* ib = image_b + (size_t)row * ID_;
#pragma unroll
    for (int c = 0; c < 12; ++c) tb[lane + 64 * c] = (bf16)xv[c];
#pragma unroll
    for (int c = 0; c < 16; ++c) ib[lane + 64 * c] = (bf16)xv[12 + c];

    double acc[NE];
#pragma unroll
    for (int e = 0; e < NE; ++e) acc[e] = 0.0;
#pragma unroll
    for (int c = 0; c < 28; ++c) {
      const double vd = (double)xv[c];
      const int idx = lane + 64 * c;
#pragma unroll
      for (int e = 0; e < NE; ++e) acc[e] = fma(vd, wg[e * GIN + idx], acc[e]);
    }
#pragma unroll
    for (int off = 32; off > 0; off >>= 1) {
#pragma unroll
      for (int e = 0; e < NE; ++e) acc[e] += __shfl_down(acc[e], off);
    }
    if (lane == 0) {
      float nz[NE];
#pragma unroll
      for (int e = 0; e < NE; ++e)
        nz[e] = (float)(acc[e] + bgd[e]) + noise[(size_t)row * NE + e];
      int i0 = 0;
#pragma unroll
      for (int e = 1; e < NE; ++e) if (nz[e] > nz[i0]) i0 = e;
      int i1 = (i0 == 0) ? 1 : 0;
#pragma unroll
      for (int e = 0; e < NE; ++e) if (e != i0 && nz[e] > nz[i1]) i1 = e;
      float tt = expf(nz[i1] - nz[i0]);
      float w0 = 1.0f / (1.0f + tt);
      float w1 = tt / (1.0f + tt);
      Top2 rec; rec.e0 = i0; rec.e1 = i1; rec.w0 = w0; rec.w1 = w1;
      top2[row] = rec;
      atomicAdd(&lcnt[i0], 1);
      atomicAdd(&lcnt[i1], 1);
    }
  }
  __syncthreads();
  if (t < NE) atomicAdd(&counts[t], lcnt[t]);
}

// ---------------- scan: offsets (padded to x128), init pos
__global__ void scan_pad(const int* __restrict__ counts, int* __restrict__ offsets,
                         int* __restrict__ padded, int* __restrict__ pos,
                         int* __restrict__ rows_list, float* __restrict__ wgt_list) {
  __shared__ int s_off[NE], s_cnt[NE], s_pad[NE];
  if (threadIdx.x == 0) {
    int off = 0;
    for (int e = 0; e < NE; ++e) {
      int c = counts[e];
      int pd = (c + 127) & ~127;
      s_cnt[e] = c; s_pad[e] = pd; s_off[e] = off;
      offsets[e] = off; padded[e] = pd; pos[e] = off;
      off += pd;
    }
    offsets[NE] = off;
  }
  __syncthreads();
  for (int e = 0; e < NE; ++e) {
    for (int i = s_cnt[e] + threadIdx.x; i < s_pad[e]; i += blockDim.x) {
      rows_list[s_off[e] + i] = 0;
      wgt_list[s_off[e] + i] = 0.0f;
    }
  }
}

// ---------------- routing pass 2: block-aggregated scatter + slot map
__global__ void route2(const Top2* __restrict__ top2, int* __restrict__ pos,
                       int* __restrict__ rows_list, float* __restrict__ wgt_list,
                       Slot2* __restrict__ slots) {
  __shared__ int lcnt[NE], lbase[NE];
  if (threadIdx.x < NE) lcnt[threadIdx.x] = 0;
  __syncthreads();
  const int r = blockIdx.x * 256 + threadIdx.x;
  Top2 tt = top2[r];
  int s0 = atomicAdd(&lcnt[tt.e0], 1);
  int s1 = atomicAdd(&lcnt[tt.e1], 1);
  __syncthreads();
  if (threadIdx.x < NE)
    lbase[threadIdx.x] = atomicAdd(&pos[threadIdx.x], lcnt[threadIdx.x]);
  __syncthreads();
  int p0 = lbase[tt.e0] + s0;
  rows_list[p0] = r; wgt_list[p0] = tt.w0;
  int p1 = lbase[tt.e1] + s1;
  rows_list[p1] = r; wgt_list[p1] = tt.w1;
  Slot2 sl; sl.p0 = p0; sl.p1 = p1;
  slots[r] = sl;
}

// ---------------- final combine: out[row] = pair[p0] + pair[p1]
__global__ __launch_bounds__(256)
void combine(const bf16* __restrict__ pairb, const Slot2* __restrict__ slots,
             float* __restrict__ out) {
  const int row = blockIdx.x;
  const Slot2 s = slots[row];
  const int t = threadIdx.x;
  const bf16x4 a = *(const bf16x4*)(pairb + (size_t)s.p0 * OD + t * 4);
  const bf16x4 b = *(const bf16x4*)(pairb + (size_t)s.p1 * OD + t * 4);
  f32x4 r;
#pragma unroll
  for (int j = 0; j < 4; ++j) r[j] = (float)a[j] + (float)b[j];
  *(f32x4*)(out + (size_t)row * OD + t * 4) = r;
}

// ========= 128x128 BK=64 SINGLE-buffered bf16 MFMA GEMM (m97 structure) =========
// r14-proven best (FFN1 963 TF, total 481us).  4 waves (2Mx2N), 64x64/wave,
// 32 KiB LDS single buffer; vmcnt(0) + 2 barriers per 64-K step.
// __launch_bounds__(256,4): r15 PROVED (256,5) forces VGPR 64->48 -> acc
// spills to scratch (WRITE_SIZE 72->406MB, MfmaUtil 10%, 2.5x slower).
// This loop needs >=64 VGPR; 4 blocks/CU is the max safe occupancy.
// Swizzle: source/read octet ^= (row&7) -> conflict-free.  1D grid XCD decode
// (A-tile's 8 N-blocks on one XCD) for MODE 1/2; 2D grid for MODE 3.
// MODE 1: expert FFN1, A gathered from TWO sources (text rows kt<12, image
//         rows kt>=12) -> h (bf16, +b1eff, relu)
// MODE 2: expert FFN2 -> pairbuf (bf16, w*(acc+b2))
// MODE 3: weight preprocess, MERGED halves (x<6: text half, else image half):
//         W1effT[e][n][coloff+k] = sum_h Xb_half[k][h] * W1T[e][n][half*HID+h]

#define BARe  do { __builtin_amdgcn_s_barrier(); __builtin_amdgcn_sched_barrier(0); } while (0)
#define VMC0  asm volatile("s_waitcnt vmcnt(0)" ::: "memory")
#define PRIO1 __builtin_amdgcn_s_setprio(1)
#define PRIO0 __builtin_amdgcn_s_setprio(0)

template<int MODE>
__global__ __launch_bounds__(256, 4)
void gemm128(const bf16* __restrict__ A, const bf16* __restrict__ A2,
             const bf16* __restrict__ BT, const float* __restrict__ bias,
             bf16* __restrict__ outb,
             const int* __restrict__ rows_list, const float* __restrict__ wgt_list,
             const int* __restrict__ offsets, const int* __restrict__ padded,
             int K, int lda, int ldb, int ldout, int coloff) {
  __shared__ bf16 As[128 * 64];   // 16 KiB
  __shared__ bf16 Bs[128 * 64];   // 16 KiB
  const int t = threadIdx.x;
  const int lane = t & 63, w = t >> 6;
  const int wm = w >> 1, wn = w & 1;

  int mblk, nblk;
  if constexpr (MODE == 3) {
    const int e = blockIdx.z;
    const int half = (blockIdx.x >= TD / 128) ? 1 : 0;
    nblk = blockIdx.x - half * (TD / 128);
    mblk = blockIdx.y;
    A += (size_t)e * HID * CB + (size_t)half * HID;   // k-offset into W1T rows
    BT += (size_t)half * TD * HID;                    // Xb image section
    outb += (size_t)e * HID * GIN;
    coloff = half * TD;
  } else {
    const int bid = blockIdx.x;
    const int xcd = bid & 7, sdec = bid >> 3;
    nblk = sdec & 7; mblk = (sdec >> 3) * 8 + xcd;
  }

  long base = 0;
  if constexpr (MODE == 1 || MODE == 2) {
    const int e = blockIdx.z;
    if (mblk * 128 >= padded[e]) return;
    base = offsets[e];
    if constexpr (MODE == 1) { BT += (size_t)e * HID * GIN; bias += e * HID; }
    else                     { BT += (size_t)e * OD * HID;  bias += e * OD; }
  }

  // staging: thread t, sub-load j (0..3): row = j*32 + (t>>3), octet c = t&7.
  // Source octet pre-swizzled: c ^ (row&7); row&7 == (t>>3)&7 for all j.
  const int scol = ((t & 7) ^ ((t >> 3) & 7)) * 8;
  const bf16* aptr[4]; const bf16* aptr2[4]; const bf16* bptr[4]; int ldso[4];
#pragma unroll
  for (int j = 0; j < 4; ++j) {
    const int row = j * 32 + (t >> 3);
    if constexpr (MODE == 1) {
      const long ga = rows_list[base + (long)mblk * 128 + row];
      aptr[j]  = A  + ga * TD  + scol;
      aptr2[j] = A2 + ga * ID_ + scol;
    } else if constexpr (MODE == 2) {
      const long ga = base + (long)mblk * 128 + row;
      aptr[j] = A + ga * lda + scol;
    } else {
      aptr[j] = A + (size_t)(mblk * 128 + row) * lda + scol;
    }
    bptr[j] = BT + (size_t)(nblk * 128 + row) * ldb + scol;
    ldso[j] = (j * 256 + t) * 8;
  }

  // fragment reads (kk=0): logical octet o = lane>>4; physical = o ^ (fr&7);
  // kk=1 flips octet bit2 -> element offset ^ 32.
  const int fr = lane & 15, hi = lane >> 4;
  const int rsw = hi ^ (fr & 7);
  int a_off[4], b_off[4];
#pragma unroll
  for (int f = 0; f < 4; ++f) {
    a_off[f] = ((wm * 64 + f * 16 + fr) * 8 + rsw) * 8;
    b_off[f] = ((wn * 64 + f * 16 + fr) * 8 + rsw) * 8;
  }

  f32x4 acc[4][4];
#pragma unroll
  for (int i = 0; i < 4; ++i)
#pragma unroll
    for (int j = 0; j < 4; ++j)
#pragma unroll
      for (int r = 0; r < 4; ++r) acc[i][j][r] = 0.0f;

  const int NKT = K >> 6;

  auto stage = [&](int kt) {
    if constexpr (MODE == 1) {
      if (kt < TD / 64) {
#pragma unroll
        for (int j = 0; j < 4; ++j) gload16(&As[ldso[j]], aptr[j] + (size_t)kt * 64);
      } else {
#pragma unroll
        for (int j = 0; j < 4; ++j)
          gload16(&As[ldso[j]], aptr2[j] + (size_t)(kt - TD / 64) * 64);
      }
    } else {
#pragma unroll
      for (int j = 0; j < 4; ++j) gload16(&As[ldso[j]], aptr[j] + (size_t)kt * 64);
    }
#pragma unroll
    for (int j = 0; j < 4; ++j) gload16(&Bs[ldso[j]], bptr[j] + (size_t)kt * 64);
  };

  stage(0);
  for (int kt = 0; kt < NKT; ++kt) {
    VMC0;                              // tile kt's 8 loads landed
    BARe;                              // visible to all waves
#pragma unroll
    for (int kk = 0; kk < 2; ++kk) {
      bf16x8 af[4], bfr[4];
#pragma unroll
      for (int f = 0; f < 4; ++f) af[f]  = *(const bf16x8*)(&As[a_off[f] ^ (kk * 32)]);
#pragma unroll
      for (int f = 0; f < 4; ++f) bfr[f] = *(const bf16x8*)(&Bs[b_off[f] ^ (kk * 32)]);
      PRIO1;
#pragma unroll
      for (int mf = 0; mf < 4; ++mf)
#pragma unroll
        for (int nf = 0; nf < 4; ++nf)
          acc[mf][nf] = __builtin_amdgcn_mfma_f32_16x16x32_bf16(af[mf], bfr[nf],
                                                                acc[mf][nf], 0, 0, 0);
      PRIO0;
    }
    BARe;                              // all waves done reading this buffer
    if (kt + 1 < NKT) stage(kt + 1);   // overwrite with next tile
  }

  // epilogue: D row = (lane>>4)*4 + r, col = lane&15
  const int row_h = hi * 4;
#pragma unroll
  for (int nf = 0; nf < 4; ++nf) {
    const int gcol = nblk * 128 + wn * 64 + nf * 16 + fr;
    float bv = 0.0f;
    if constexpr (MODE != 3) bv = bias[gcol];
#pragma unroll
    for (int mf = 0; mf < 4; ++mf) {
      const int rbase = wm * 64 + mf * 16 + row_h;
#pragma unroll
      for (int r = 0; r < 4; ++r) {
        const int rit = rbase + r;
        float v = acc[mf][nf][r] + bv;
        if constexpr (MODE == 1) {
          outb[(size_t)(base + (long)mblk * 128 + rit) * ldout + gcol] =
              (bf16)fmaxf(v, 0.0f);
        } else if constexpr (MODE == 2) {
          const long li = base + (long)mblk * 128 + rit;
          const float wgt = wgt_list[li];
          outb[(size_t)li * ldout + gcol] = (bf16)(wgt * v);
        } else {
          outb[((size_t)mblk * 128 + rit) * ldout + coloff + gcol] = (bf16)v;
        }
      }
    }
  }
}

extern "C" void kernel_launch(void* const* d_in, const int* in_sizes, int n_in,
                              void* d_out, int out_size, void* d_ws, size_t ws_size,
                              hipStream_t stream) {
  const float* text  = (const float*)d_in[0];
  const float* image = (const float*)d_in[1];
  const float* noise = (const float*)d_in[2];
  const float* Wt    = (const float*)d_in[3];
  const float* bt    = (const float*)d_in[4];
  const float* Wi    = (const float*)d_in[5];
  const float* bi    = (const float*)d_in[6];
  const float* Wg    = (const float*)d_in[7];
  const float* bg    = (const float*)d_in[8];
  const float* W1    = (const float*)d_in[9];
  const float* b1    = (const float*)d_in[10];
  const float* W2    = (const float*)d_in[11];
  const float* b2    = (const float*)d_in[12];
  float* out = (float*)d_out;

  char* p = (char*)d_ws;
  auto alloc = [&](size_t bytes) {
    char* r = p; p += (bytes + 255) & ~(size_t)255; return r;
  };

  bf16* text_b  = (bf16*)alloc((size_t)BB * TD * 2);
  bf16* image_b = (bf16*)alloc((size_t)BB * ID_ * 2);

  // union region u1: {W1T, W1effT, Xb} (preprocess + FFN1 era) / pairb (FFN2 era).
  // W1T 33.55MB + W1effT 29.36MB + Xb 3.67MB = 66.6MB <= pairb 69.2MB.
  // pairb is first written in FFN2, which launches after the last reader of
  // W1T/Xb (preprocess) and W1effT (FFN1) -- stream-ordered, no overlap.
  const size_t sz_w1t  = (size_t)NE * HID * CB * 2;
  const size_t sz_w1e  = (size_t)NE * HID * GIN * 2;
  const size_t sz_pair = (size_t)CAPT * OD * 2;
  char* u1 = alloc(sz_pair);
  bf16* W1T    = (bf16*)u1;
  bf16* W1effT = (bf16*)(u1 + sz_w1t);
  bf16* Xb     = (bf16*)(u1 + sz_w1t + sz_w1e);
  bf16* pairb  = (bf16*)u1;

  bf16*   W2T      = (bf16*)alloc((size_t)NE * OD * HID * 2);
  bf16*   hbuf     = (bf16*)alloc((size_t)CAPT * HID * 2);
  double* WgF      = (double*)alloc((size_t)NE * GIN * 8);
  double* bgd      = (double*)alloc((size_t)NE * 8);
  float*  b1e      = (float*)alloc((size_t)NE * HID * 4);
  Top2*   top2     = (Top2*)alloc((size_t)BB * sizeof(Top2));
  Slot2*  slots    = (Slot2*)alloc((size_t)BB * sizeof(Slot2));
  int*    counts   = (int*)alloc(NE * 4);
  int*    offsets  = (int*)alloc((NE + 1) * 4);
  int*    padded   = (int*)alloc(NE * 4);
  int*    pos      = (int*)alloc(NE * 4);
  int*    rows_list= (int*)alloc((size_t)CAPT * 4);
  float*  wgt_list = (float*)alloc((size_t)CAPT * 4);

  hipMemsetAsync(counts, 0, NE * 4, stream);

  transpose_cvt<<<dim3(HID / 64, CB / 64, NE), 256, 0, stream>>>(W1, W1T, CB, HID);
  transpose_cvt<<<dim3(OD / 64, HID / 64, NE), 256, 0, stream>>>(W2, W2T, HID, OD);
  cast_x<<<(GIN * HID) / 8 / 256, 256, 0, stream>>>(Wt, Wi, Xb);

  fuse_w<<<((GIN + 1) * NE + 3) / 4, 256, 0, stream>>>(
      Wt, Wi, Wg, bt, bi, bg, WgF, bgd);
  b1eff_k<<<NE * HID / 256, 256, 0, stream>>>(W1T, bt, bi, b1, b1e);
  route1<<<BB / 64, 1024, 0, stream>>>(text, image, noise, WgF, bgd,
                                       text_b, image_b, top2, counts);
  scan_pad<<<1, 256, 0, stream>>>(counts, offsets, padded, pos, rows_list, wgt_list);
  route2<<<BB / 256, 256, 0, stream>>>(top2, pos, rows_list, wgt_list, slots);

  // weight preprocess (merged halves): x<6 -> text half, x>=6 -> image half
  gemm128<3><<<dim3(GIN / 128, HID / 128, NE), 256, 0, stream>>>(
      W1T, nullptr, Xb, nullptr, W1effT, nullptr, nullptr, nullptr, nullptr,
      HID, CB, HID, GIN, 0);
  // expert FFN1 (gathered, two-source A, K=1792) -> h
  gemm128<1><<<dim3(1024, 1, NE), 256, 0, stream>>>(
      text_b, image_b, W1effT, b1e, hbuf, rows_list, nullptr, offsets, padded,
      GIN, 0, GIN, HID, 0);
  // expert FFN2 -> pair buffer (plain bf16 stores)
  gemm128<2><<<dim3(1024, 1, NE), 256, 0, stream>>>(
      hbuf, nullptr, W2T, b2, pairb, rows_list, wgt_list, offsets, padded,
      HID, HID, HID, OD, 0);
  // final: out[row] = pair[p0] + pair[p1]
  combine<<<BB, 256, 0, stream>>>(pairb, slots, out);
}